// Round 1
// baseline (188.322 us; speedup 1.0000x reference)
//
#include <hip/hip_runtime.h>
#include <math.h>

#define TWO_PI 6.28318530717958647692f

__device__ __forceinline__ void cmac(float2& a, const float2 b, const float2 c) {
  a.x = fmaf(b.x, c.x, fmaf(-b.y, c.y, a.x));
  a.y = fmaf(b.x, c.y, fmaf(b.y, c.x, a.y));
}

// ---------------------------------------------------------------------------
// F1: pruned DFT along H.  x:(B,C,256,256,4) -> G[(b*32+c)*2+dual][k(64)][y(256)] complex
// grid 4096 = 128 images * 32 w-tiles(8), block 256
// ---------------------------------------------------------------------------
__global__ __launch_bounds__(256) void f1_dft_h(const float* __restrict__ x,
                                                float* __restrict__ G) {
  __shared__ float2 tw[256];
  __shared__ float2 yf[64][4][2][8];  // [n1][r][dual][w] : slice per n1 contiguous
  const int t = threadIdx.x;
  {
    float sv, cv;
    sincosf(-TWO_PI * (float)t * (1.0f / 256.0f), &sv, &cv);
    tw[t] = make_float2(cv, sv);
  }
  const int bid = blockIdx.x;
  const int img = bid >> 5;            // b*32+c
  const int w0  = (bid & 31) << 3;     // 8-column tile
  const float4* __restrict__ xb = (const float4*)x + (size_t)img * 65536 + w0;
  {
    const int wl  = t & 7;
    const int n1g = t >> 3;            // [0,32)
#pragma unroll
    for (int ii = 0; ii < 2; ++ii) {
      const int n1 = n1g * 2 + ii;
      const float4 v0 = xb[(size_t)(n1)*256 + wl];
      const float4 v1 = xb[(size_t)(n1 + 64) * 256 + wl];
      const float4 v2 = xb[(size_t)(n1 + 128) * 256 + wl];
      const float4 v3 = xb[(size_t)(n1 + 192) * 256 + wl];
      // dual 0: (comp0, comp3)
      {
        const float sx = v0.x + v2.x, sy = v0.w + v2.w;
        const float dx = v0.x - v2.x, dy = v0.w - v2.w;
        const float ux = v1.x + v3.x, uy = v1.w + v3.w;
        const float ex = v1.x - v3.x, ey = v1.w - v3.w;
        yf[n1][0][0][wl] = make_float2(sx + ux, sy + uy);
        yf[n1][2][0][wl] = make_float2(sx - ux, sy - uy);
        yf[n1][1][0][wl] = make_float2(dx + ey, dy - ex);  // d - i*e
        yf[n1][3][0][wl] = make_float2(dx - ey, dy + ex);  // d + i*e
      }
      // dual 1: (comp1, comp2)
      {
        const float sx = v0.y + v2.y, sy = v0.z + v2.z;
        const float dx = v0.y - v2.y, dy = v0.z - v2.z;
        const float ux = v1.y + v3.y, uy = v1.z + v3.z;
        const float ex = v1.y - v3.y, ey = v1.z - v3.z;
        yf[n1][0][1][wl] = make_float2(sx + ux, sy + uy);
        yf[n1][2][1][wl] = make_float2(sx - ux, sy - uy);
        yf[n1][1][1][wl] = make_float2(dx + ey, dy - ex);
        yf[n1][3][1][wl] = make_float2(dx - ey, dy + ex);
      }
    }
  }
  __syncthreads();
  const int wl    = t & 7;
  const int dual  = (t >> 3) & 1;
  const int kslot = t >> 4;            // [0,16)
  const int r     = kslot & 3;
  int kk[4];
#pragma unroll
  for (int m = 0; m < 4; ++m) {
    const int ki = kslot + (m << 4);
    kk[m] = (ki < 32) ? ki : ki + 192;
  }
  float2 acc[4];
  int idx[4];
#pragma unroll
  for (int m = 0; m < 4; ++m) { acc[m] = make_float2(0.f, 0.f); idx[m] = 0; }
#pragma unroll 4
  for (int n1 = 0; n1 < 64; ++n1) {
    const float2 yv = yf[n1][r][dual][wl];
#pragma unroll
    for (int m = 0; m < 4; ++m) {
      const float2 tv = tw[idx[m]];
      cmac(acc[m], yv, tv);
      idx[m] = (idx[m] + kk[m]) & 255;
    }
  }
  float2* __restrict__ Gp = (float2*)G;
  const size_t base = ((size_t)(img * 2 + dual) * 64) * 256 + w0 + wl;
#pragma unroll
  for (int m = 0; m < 4; ++m) {
    Gp[base + (size_t)(kslot + (m << 4)) * 256] = acc[m];
  }
}

// ---------------------------------------------------------------------------
// F2: pruned DFT along W on kept rows. G -> modes_in[b][s][c][x'][y'] (real f32)
// grid 4096 (4 rows/block of 16384 rows), block 256
// ---------------------------------------------------------------------------
__global__ __launch_bounds__(256) void f2_dft_w(const float* __restrict__ G,
                                                float* __restrict__ mi) {
  __shared__ float2 tw[256];
  __shared__ float2 yf[4][64][5];  // [trow][n1][r] pad 5 to break write conflicts
  const int t = threadIdx.x;
  {
    float sv, cv;
    sincosf(-TWO_PI * (float)t * (1.0f / 256.0f), &sv, &cv);
    tw[t] = make_float2(cv, sv);
  }
  const int trow = t >> 6, lane = t & 63;
  const int row = blockIdx.x * 4 + trow;   // ((img*2+dual)*64 + kx)
  const float2* __restrict__ Gp = (const float2*)G + (size_t)row * 256;
  {
    const float2 z0 = Gp[lane], z1 = Gp[lane + 64], z2 = Gp[lane + 128], z3 = Gp[lane + 192];
    const float sx = z0.x + z2.x, sy = z0.y + z2.y;
    const float dx = z0.x - z2.x, dy = z0.y - z2.y;
    const float ux = z1.x + z3.x, uy = z1.y + z3.y;
    const float ex = z1.x - z3.x, ey = z1.y - z3.y;
    yf[trow][lane][0] = make_float2(sx + ux, sy + uy);
    yf[trow][lane][2] = make_float2(sx - ux, sy - uy);
    yf[trow][lane][1] = make_float2(dx + ey, dy - ex);
    yf[trow][lane][3] = make_float2(dx - ey, dy + ex);
  }
  __syncthreads();
  const int kyi = lane;
  const int ky = (kyi < 32) ? kyi : kyi + 192;
  const int r = kyi & 3;
  float2 acc = make_float2(0.f, 0.f);
  int idx = 0;
#pragma unroll 4
  for (int n1 = 0; n1 < 64; ++n1) {
    const float2 yv = yf[trow][n1][r];
    const float2 tv = tw[idx];
    cmac(acc, yv, tv);
    idx = (idx + ky) & 255;
  }
  const int kx = row & 63;
  const int dual = (row >> 6) & 1;
  const int bc = row >> 7;
  const int b = bc >> 5, cc = bc & 31;
  const int sRe = dual ? 1 : 0;
  const int sIm = dual ? 2 : 3;
  const size_t moff = (size_t)kx * 64 + kyi;
  mi[(((size_t)(b * 4 + sRe)) * 32 + cc) * 4096 + moff] = acc.x;
  mi[(((size_t)(b * 4 + sIm)) * 32 + cc) * 4096 + moff] = acc.y;
}

// ---------------------------------------------------------------------------
// EIN: per-mode Clifford mix. modes_in + weights -> modes_out[b][r][o][x'][y']
// The 4x4 (sign, j) block structure is inlined; weights streamed exactly once.
// grid 512 = 256 mode-tiles(16) * 2 o-halves, block 256
// ---------------------------------------------------------------------------
__global__ __launch_bounds__(256) void ein_k(const float* __restrict__ mi,
                                             const float* __restrict__ wgt,
                                             float* __restrict__ mo) {
  __shared__ float si[4][128][16];  // [b][i=s*32+c][q]
  const int t = threadIdx.x;
  const int bid = blockIdx.x;
  const int m0 = (bid >> 1) << 4;
  const int oh = bid & 1;
  for (int idx = t; idx < 8192; idx += 256) {
    const int q = idx & 15, i = (idx >> 4) & 127, b = idx >> 11;
    si[b][i][q] = mi[((size_t)b * 128 + i) * 4096 + m0 + q];
  }
  __syncthreads();
  const int q = t & 15;
  const int o = oh * 16 + (t >> 4);
  float acc[4][4];
#pragma unroll
  for (int b = 0; b < 4; ++b)
#pragma unroll
    for (int r = 0; r < 4; ++r) acc[b][r] = 0.f;
#pragma unroll 2
  for (int c = 0; c < 32; ++c) {
    float wv[4];
#pragma unroll
    for (int j = 0; j < 4; ++j)
      wv[j] = wgt[(((size_t)j * 32 + o) * 32 + c) * 4096 + m0 + q];
#pragma unroll
    for (int b = 0; b < 4; ++b) {
      const float iv0 = si[b][c][q];
      const float iv1 = si[b][32 + c][q];
      const float iv2 = si[b][64 + c][q];
      const float iv3 = si[b][96 + c][q];
      acc[b][0] += wv[0] * iv0 + wv[1] * iv1 + wv[2] * iv2 - wv[3] * iv3;
      acc[b][1] += wv[1] * iv0 + wv[0] * iv1 - wv[3] * iv2 + wv[2] * iv3;
      acc[b][2] += wv[2] * iv0 + wv[3] * iv1 + wv[0] * iv2 - wv[1] * iv3;
      acc[b][3] += wv[3] * iv0 + wv[2] * iv1 - wv[1] * iv2 + wv[0] * iv3;
    }
  }
#pragma unroll
  for (int b = 0; b < 4; ++b)
#pragma unroll
    for (int r = 0; r < 4; ++r)
      mo[(((size_t)b * 4 + r) * 32 + o) * 4096 + m0 + q] = acc[b][r];
}

// ---------------------------------------------------------------------------
// I1: inverse DFT along W (64 -> 256). modes_out -> T[(bo*2+dual)*64+kx][y(256)]
// grid 4096 (4 rows/block), block 256
// ---------------------------------------------------------------------------
__global__ __launch_bounds__(256) void i1_idft_w(const float* __restrict__ mo,
                                                 float* __restrict__ T) {
  __shared__ float2 twc[256];
  __shared__ float2 srow[4][64];
  const int t = threadIdx.x;
  {
    float sv, cv;
    sincosf(TWO_PI * (float)t * (1.0f / 256.0f), &sv, &cv);
    twc[t] = make_float2(cv, sv);
  }
  const int trow = t >> 6, lane = t & 63;
  const int row = blockIdx.x * 4 + trow;  // ((bo*2+dual)*64 + kx)
  const int kx = row & 63;
  const int dual = (row >> 6) & 1;
  const int bo = row >> 7;
  const int b = bo >> 5, o = bo & 31;
  const int rA = dual ? 1 : 0;
  const int rB = dual ? 2 : 3;
  const size_t ibase = (size_t)kx * 64 + lane;
  srow[trow][lane] = make_float2(mo[(((size_t)b * 4 + rA) * 32 + o) * 4096 + ibase],
                                 mo[(((size_t)b * 4 + rB) * 32 + o) * 4096 + ibase]);
  __syncthreads();
  const int n1 = lane;
  float2 V[4];
#pragma unroll
  for (int r = 0; r < 4; ++r) {
    float2 acc = make_float2(0.f, 0.f);
#pragma unroll 4
    for (int tt = 0; tt < 16; ++tt) {
      const int kyi = r + 4 * tt;
      const int ky = (kyi < 32) ? kyi : kyi + 192;
      const float2 ov = srow[trow][kyi];
      const float2 tv = twc[(ky * n1) & 255];
      cmac(acc, ov, tv);
    }
    V[r] = acc;
  }
  const float sx = V[0].x + V[2].x, sy = V[0].y + V[2].y;
  const float dx = V[0].x - V[2].x, dy = V[0].y - V[2].y;
  const float ux = V[1].x + V[3].x, uy = V[1].y + V[3].y;
  const float ex = V[1].x - V[3].x, ey = V[1].y - V[3].y;
  float2* __restrict__ Tp = (float2*)T + (size_t)row * 256;
  Tp[n1]       = make_float2(sx + ux, sy + uy);            // n2=0
  Tp[n1 + 64]  = make_float2(dx - ey, dy + ex);            // + i*e
  Tp[n1 + 128] = make_float2(sx - ux, sy - uy);
  Tp[n1 + 192] = make_float2(dx + ey, dy - ex);            // - i*e
}

// ---------------------------------------------------------------------------
// I2: inverse DFT along H (64 -> 256) + interleave + 1/65536 scale -> out
// grid 2048 = 128 images * 16 w-tiles(16), block 256
// ---------------------------------------------------------------------------
__global__ __launch_bounds__(256) void i2_idft_h(const float* __restrict__ T,
                                                 float* __restrict__ out) {
  __shared__ float2 twc[256];
  __shared__ float2 Tl[2][64][16];
  const int t = threadIdx.x;
  {
    float sv, cv;
    sincosf(TWO_PI * (float)t * (1.0f / 256.0f), &sv, &cv);
    twc[t] = make_float2(cv, sv);
  }
  const int bid = blockIdx.x;
  const int bo = bid >> 4;
  const int w0 = (bid & 15) << 4;
  const float2* __restrict__ Tp = (const float2*)T + (size_t)bo * 2 * 16384;
  for (int idx = t; idx < 2048; idx += 256) {
    const int ww = idx & 15, kxi = (idx >> 4) & 63, dual = idx >> 10;
    Tl[dual][kxi][ww] = Tp[((size_t)dual * 64 + kxi) * 256 + w0 + ww];
  }
  __syncthreads();
  const int wl = t & 15;
  const int n1g = t >> 4;
  float4* __restrict__ op = (float4*)out + (size_t)bo * 65536 + w0 + wl;
  const float sc = 1.0f / 65536.0f;
#pragma unroll
  for (int ii = 0; ii < 4; ++ii) {
    const int n1 = n1g * 4 + ii;
    float2 res[2][4];
#pragma unroll
    for (int dual = 0; dual < 2; ++dual) {
      float2 V[4];
#pragma unroll
      for (int r = 0; r < 4; ++r) {
        float2 acc = make_float2(0.f, 0.f);
#pragma unroll 4
        for (int tt = 0; tt < 16; ++tt) {
          const int kxi2 = r + 4 * tt;
          const int kxf = (kxi2 < 32) ? kxi2 : kxi2 + 192;
          const float2 ov = Tl[dual][kxi2][wl];
          const float2 tv = twc[(kxf * n1) & 255];
          cmac(acc, ov, tv);
        }
        V[r] = acc;
      }
      const float sx = V[0].x + V[2].x, sy = V[0].y + V[2].y;
      const float dx = V[0].x - V[2].x, dy = V[0].y - V[2].y;
      const float ux = V[1].x + V[3].x, uy = V[1].y + V[3].y;
      const float ex = V[1].x - V[3].x, ey = V[1].y - V[3].y;
      res[dual][0] = make_float2(sx + ux, sy + uy);
      res[dual][1] = make_float2(dx - ey, dy + ex);
      res[dual][2] = make_float2(sx - ux, sy - uy);
      res[dual][3] = make_float2(dx + ey, dy - ex);
    }
#pragma unroll
    for (int n2 = 0; n2 < 4; ++n2) {
      const int h = n1 + (n2 << 6);
      const float2 o1 = res[0][n2], o2 = res[1][n2];
      op[(size_t)h * 256] = make_float4(o1.x * sc, o2.x * sc, o2.y * sc, o1.y * sc);
    }
  }
}

extern "C" void kernel_launch(void* const* d_in, const int* in_sizes, int n_in,
                              void* d_out, int out_size, void* d_ws, size_t ws_size,
                              hipStream_t stream) {
  const float* x = (const float*)d_in[0];
  const float* wgt = (const float*)d_in[1];
  float* out = (float*)d_out;
  float* G  = (float*)d_ws;        // 8,388,608 floats (33.5 MB), reused as T
  float* mi = G + 8388608;         // 2,097,152 floats
  float* mo = mi + 2097152;        // 2,097,152 floats

  hipLaunchKernelGGL(f1_dft_h, dim3(4096), dim3(256), 0, stream, x, G);
  hipLaunchKernelGGL(f2_dft_w, dim3(4096), dim3(256), 0, stream, G, mi);
  hipLaunchKernelGGL(ein_k,    dim3(512),  dim3(256), 0, stream, mi, wgt, mo);
  hipLaunchKernelGGL(i1_idft_w, dim3(4096), dim3(256), 0, stream, mo, G);
  hipLaunchKernelGGL(i2_idft_h, dim3(2048), dim3(256), 0, stream, G, out);
}